// Round 4
// baseline (162.262 us; speedup 1.0000x reference)
//
#include <hip/hip_runtime.h>
#include <hip/hip_bf16.h>

// KroneckerProjection: out = X @ kron(A,B), factored.
//   Step 1 (fp32 VALU, verified): T[m][j][k] = sum_i x[m][i*16+k]*A[i][j]
//   Step 2 (bf16 MFMA):           out[m][j*512+l] = sum_k T[m][j][k]*B[k][l]
// Block = 256 thr (4 waves) owns 16 rows. Step 1: wave w does rows 4w..4w+3
// with lane=(r,k), T[16]/lane (identical to round-3 code). T -> padded LDS.
// Step 2: mfma_f32_16x16x32_bf16 with K=16 zero-padded (lanes q>=2 supply
// zero frags). Wave w covers cols [w*128,(w+1)*128): 16 j x 8 chunks = 128
// MFMAs; D stored as dword (4x64B segments, L2 write-combines lines).
// Only U and B are rounded to bf16 (x*A stays fp32): est absmax ~1-2 << 7.48.

#define DIN   2048
#define DOUT  8192
#define SM    260      // T_lds m-stride in dwords: 16B-aligned, bank-spread

typedef __attribute__((ext_vector_type(8))) short bf16x8;
typedef __attribute__((ext_vector_type(4))) float f32x4;

__device__ __forceinline__ short f2bf(float f) {
    __hip_bfloat16 h = __float2bfloat16(f);   // RNE
    short s;
    __builtin_memcpy(&s, &h, 2);
    return s;
}

__global__ __launch_bounds__(256, 3)
void kron_mfma_kernel(const float* __restrict__ x,
                      const float* __restrict__ A,
                      const float* __restrict__ B,
                      float* __restrict__ out)
{
    __shared__ float T_lds[16 * SM];          // 16.6 KiB

    const int t    = threadIdx.x;
    const int w    = t >> 6;                  // wave 0..3
    const int lane = t & 63;
    const int row0 = blockIdx.x * 16;

    // ---- Step 1: rows row0+4w .. +3, lane=(r,k) — round-3 verified code
    const int r = lane >> 4, k = lane & 15;
    float T[16];
#pragma unroll
    for (int j = 0; j < 16; ++j) T[j] = 0.f;

    const float* xr = x + (size_t)(row0 + 4 * w + r) * DIN + k;
#pragma unroll 8
    for (int i = 0; i < 128; ++i) {
        const float xv = xr[i * 16];          // coalesced 64B segments
        const float* Ar = A + i * 16;         // uniform -> s_load
#pragma unroll
        for (int j = 0; j < 16; ++j) T[j] = fmaf(xv, Ar[j], T[j]);
    }
    {
        float* Tm = T_lds + (4 * w + r) * SM + k;
#pragma unroll
        for (int j = 0; j < 16; ++j) Tm[j * 16] = T[j];
    }

    // ---- B-frags for this wave's col range [w*128, w*128+128), built once.
    // B-op layout: elem e holds B[k=(lane>>4)*8+e][col=c*16+(lane&15)];
    // k>=16 (q>=2) lanes are zero (K padding).
    const int q = lane >> 4;
    const int n = lane & 15;
    bf16x8 bfrag[8];
#pragma unroll
    for (int c = 0; c < 8; ++c) {
        bf16x8 f = (bf16x8)0;
        if (q < 2) {
            const float* Bp = B + (size_t)(q * 8) * 512 + w * 128 + c * 16 + n;
#pragma unroll
            for (int e = 0; e < 8; ++e) f[e] = f2bf(Bp[(size_t)e * 512]);
        }
        bfrag[c] = f;
    }

    __syncthreads();

    // ---- A-frags: elem e holds U[m=lane&15][j][k=q*8+e]; q>=2 zero.
    bf16x8 afrag[16];
#pragma unroll
    for (int j = 0; j < 16; ++j) {
        bf16x8 f = (bf16x8)0;
        if (q < 2) {
            const float* Tp = T_lds + n * SM + j * 16 + q * 8;
#pragma unroll
            for (int e = 0; e < 8; ++e) f[e] = f2bf(Tp[e]);
        }
        afrag[j] = f;
    }

    // ---- Step 2: D = U_j (16x16, K pad to 32) x B-chunk (16x16)
    // D layout (m89-verified): col = lane&15, row = q*4 + reg.
    float* ob = out + (size_t)(row0 + q * 4) * DOUT + w * 128 + n;
#pragma unroll
    for (int j = 0; j < 16; ++j) {
        float* oj = ob + j * 512;
#pragma unroll
        for (int c = 0; c < 8; ++c) {
            f32x4 d = {0.f, 0.f, 0.f, 0.f};
            d = __builtin_amdgcn_mfma_f32_16x16x32_bf16(afrag[j], bfrag[c], d,
                                                        0, 0, 0);
            float* oc = oj + c * 16;
            oc[0]             = d[0];
            oc[(size_t)DOUT]     = d[1];
            oc[(size_t)2 * DOUT] = d[2];
            oc[(size_t)3 * DOUT] = d[3];
        }
    }
}

extern "C" void kernel_launch(void* const* d_in, const int* in_sizes, int n_in,
                              void* d_out, int out_size, void* d_ws, size_t ws_size,
                              hipStream_t stream) {
    const float* x = (const float*)d_in[0];
    const float* A = (const float*)d_in[1];
    const float* B = (const float*)d_in[2];
    float* out = (float*)d_out;

    const int nrows = in_sizes[0] / DIN;      // 16384
    const int grid  = nrows / 16;             // 1024 blocks, 16 rows each

    kron_mfma_kernel<<<dim3(grid), dim3(256), 0, stream>>>(x, A, B, out);
}

// Round 5
// 141.728 us; speedup vs baseline: 1.1449x; 1.1449x over previous
//
#include <hip/hip_runtime.h>
#include <hip/hip_bf16.h>

// KroneckerProjection: out = X @ kron(A,B), factored.
//   Step 1 (fp32 VALU, verified r3/r4): T[m][j][k] = sum_i x[m][i*16+k]*A[i][j]
//   Step 2 (bf16 MFMA, layouts verified r4): out[m][j*512+l] = sum_k T[m][j][k]*B[k][l]
// New vs r4: D is transposed through a per-wave LDS tile so global stores are
// float4 / 512B-contiguous segments (r3's store shape), instead of r4's 64B
// row-scatter dword stores. afrag built on-demand per j (low VGPR, no spill).
// Block = 256 thr (4 waves) owns 16 rows; wave w owns cols l in [w*128,(w+1)*128).

#define DIN   2048
#define DOUT  8192
#define TS    268      // T_lds row stride (dwords): 16B-aligned, bank-spread
#define TRS   132      // transpose tile row stride (dwords): 16B-aligned

typedef __attribute__((ext_vector_type(8))) short bf16x8;
typedef __attribute__((ext_vector_type(4))) float f32x4;

__device__ __forceinline__ short f2bf(float f) {
    __hip_bfloat16 h = __float2bfloat16(f);   // RNE
    short s;
    __builtin_memcpy(&s, &h, 2);
    return s;
}

__global__ __launch_bounds__(256, 3)
void kron_mfma2_kernel(const float* __restrict__ x,
                       const float* __restrict__ A,
                       const float* __restrict__ B,
                       float* __restrict__ out)
{
    __shared__ __align__(16) float T_lds[16 * TS];        // 17.2 KiB
    __shared__ __align__(16) float trans[4][16 * TRS];    // 33.8 KiB

    const int t    = threadIdx.x;
    const int w    = t >> 6;                  // wave 0..3
    const int lane = t & 63;
    const int row0 = blockIdx.x * 16;

    // ---- Step 1: rows row0+4w..+3, lane=(r,k) — verified fp32 path
    const int r = lane >> 4, k = lane & 15;
    {
        float T[16];
#pragma unroll
        for (int j = 0; j < 16; ++j) T[j] = 0.f;

        const float* xr = x + (size_t)(row0 + 4 * w + r) * DIN + k;
#pragma unroll 8
        for (int i = 0; i < 128; ++i) {
            const float xv = xr[i * 16];      // coalesced 64B segments
            const float* Ar = A + i * 16;     // uniform -> s_load
#pragma unroll
            for (int j = 0; j < 16; ++j) T[j] = fmaf(xv, Ar[j], T[j]);
        }
        float* Tm = T_lds + (4 * w + r) * TS + k;
#pragma unroll
        for (int j = 0; j < 16; ++j) Tm[j * 16] = T[j];
    }

    // ---- B-frags (verified r4): elem e = B[k=q*8+e][w*128 + c*16 + n]; q>=2 zero
    const int q = lane >> 4;
    const int n = lane & 15;
    bf16x8 bfrag[8];
#pragma unroll
    for (int c = 0; c < 8; ++c) {
        bf16x8 f = (bf16x8)0;
        if (q < 2) {
            const float* Bp = B + (size_t)(q * 8) * 512 + w * 128 + c * 16 + n;
#pragma unroll
            for (int e = 0; e < 8; ++e) f[e] = f2bf(Bp[(size_t)e * 512]);
        }
        bfrag[c] = f;
    }

    __syncthreads();   // all T rows visible to all waves

    float* tw = trans[w];

    // ---- Step 2 main loop over j
#pragma unroll 2
    for (int j = 0; j < 16; ++j) {
        // afrag on demand (verified layout): elem e = U[m=n][k=q*8+e]; q>=2 zero
        bf16x8 af = (bf16x8)0;
        if (q < 2) {
            const float* Tp = T_lds + n * TS + j * 16 + q * 8;
            float4 t0 = *(const float4*)(Tp);
            float4 t1 = *(const float4*)(Tp + 4);
            af[0] = f2bf(t0.x); af[1] = f2bf(t0.y);
            af[2] = f2bf(t0.z); af[3] = f2bf(t0.w);
            af[4] = f2bf(t1.x); af[5] = f2bf(t1.y);
            af[6] = f2bf(t1.z); af[7] = f2bf(t1.w);
        }

        // MFMA per 16-col chunk; D(lane(q,n), reg) = out[row=q*4+reg][col=c*16+n]
        // -> write transposed into LDS tile (2-way banks = free)
#pragma unroll
        for (int c = 0; c < 8; ++c) {
            f32x4 d = {0.f, 0.f, 0.f, 0.f};
            d = __builtin_amdgcn_mfma_f32_16x16x32_bf16(af, bfrag[c], d, 0, 0, 0);
            float* tp = tw + c * 16 + n;
            tp[(q * 4 + 0) * TRS] = d[0];
            tp[(q * 4 + 1) * TRS] = d[1];
            tp[(q * 4 + 2) * TRS] = d[2];
            tp[(q * 4 + 3) * TRS] = d[3];
        }

        // read back coalesced and store: 8 instrs, each 2 rows x 512B contiguous
        const int rrow = (lane >> 5);         // 0/1: row within pair
        const int c4   = (lane & 31) * 4;     // col offset within 128-col chunk
        float* ob = out + (size_t)row0 * DOUT + j * 512 + w * 128 + c4;
#pragma unroll
        for (int rp = 0; rp < 8; ++rp) {
            const int row = 2 * rp + rrow;
            float4 v = *(const float4*)(tw + row * TRS + c4);
            *(float4*)(ob + (size_t)row * DOUT) = v;
        }
    }
}

extern "C" void kernel_launch(void* const* d_in, const int* in_sizes, int n_in,
                              void* d_out, int out_size, void* d_ws, size_t ws_size,
                              hipStream_t stream) {
    const float* x = (const float*)d_in[0];
    const float* A = (const float*)d_in[1];
    const float* B = (const float*)d_in[2];
    float* out = (float*)d_out;

    const int nrows = in_sizes[0] / DIN;      // 16384
    const int grid  = nrows / 16;             // 1024 blocks, 16 rows each

    kron_mfma2_kernel<<<dim3(grid), dim3(256), 0, stream>>>(x, A, B, out);
}

// Round 6
// 126.674 us; speedup vs baseline: 1.2809x; 1.1188x over previous
//
#include <hip/hip_runtime.h>
#include <hip/hip_bf16.h>

// KroneckerProjection: out = X @ kron(A,B), factored.
//   Step 1 (fp32 VALU, verified): T[m][j][k] = sum_i x[m][i*16+k]*A[i][j]
//   Step 2 (bf16 MFMA, verified):  out[m][j*512+l] = sum_k T[m][j][k]*B[k][l]
// r6 = r5 with NONTEMPORAL output stores (MUBUF nt: write-around, no L2/L3
// allocate). Output has zero reuse and all stores are full-line; if the
// ~4.7 TB/s plateau common to r1-r5 is L2 fetch-on-write / L3 dirty-evict
// throttling, nt removes it. Pure A/B vs r5 — nothing else changed.

#define DIN   2048
#define DOUT  8192
#define TS    268      // T_lds row stride (dwords): 16B-aligned, bank-spread
#define TRS   132      // transpose tile row stride (dwords): 16B-aligned

typedef __attribute__((ext_vector_type(8))) short bf16x8;
typedef __attribute__((ext_vector_type(4))) float f32x4;

__device__ __forceinline__ short f2bf(float f) {
    __hip_bfloat16 h = __float2bfloat16(f);   // RNE
    short s;
    __builtin_memcpy(&s, &h, 2);
    return s;
}

__global__ __launch_bounds__(256, 3)
void kron_mfma3_kernel(const float* __restrict__ x,
                       const float* __restrict__ A,
                       const float* __restrict__ B,
                       float* __restrict__ out)
{
    __shared__ __align__(16) float T_lds[16 * TS];        // 17.2 KiB
    __shared__ __align__(16) float trans[4][16 * TRS];    // 33.8 KiB

    const int t    = threadIdx.x;
    const int w    = t >> 6;                  // wave 0..3
    const int lane = t & 63;
    const int row0 = blockIdx.x * 16;

    // ---- Step 1: rows row0+4w..+3, lane=(r,k) — verified fp32 path
    const int r = lane >> 4, k = lane & 15;
    {
        float T[16];
#pragma unroll
        for (int j = 0; j < 16; ++j) T[j] = 0.f;

        const float* xr = x + (size_t)(row0 + 4 * w + r) * DIN + k;
#pragma unroll 8
        for (int i = 0; i < 128; ++i) {
            const float xv = xr[i * 16];      // coalesced 64B segments
            const float* Ar = A + i * 16;     // uniform -> s_load
#pragma unroll
            for (int j = 0; j < 16; ++j) T[j] = fmaf(xv, Ar[j], T[j]);
        }
        float* Tm = T_lds + (4 * w + r) * TS + k;
#pragma unroll
        for (int j = 0; j < 16; ++j) Tm[j * 16] = T[j];
    }

    // ---- B-frags (verified): elem e = B[k=q*8+e][w*128 + c*16 + n]; q>=2 zero
    const int q = lane >> 4;
    const int n = lane & 15;
    bf16x8 bfrag[8];
#pragma unroll
    for (int c = 0; c < 8; ++c) {
        bf16x8 f = (bf16x8)0;
        if (q < 2) {
            const float* Bp = B + (size_t)(q * 8) * 512 + w * 128 + c * 16 + n;
#pragma unroll
            for (int e = 0; e < 8; ++e) f[e] = f2bf(Bp[(size_t)e * 512]);
        }
        bfrag[c] = f;
    }

    __syncthreads();   // all T rows visible to all waves

    float* tw = trans[w];

    // ---- Step 2 main loop over j
#pragma unroll 2
    for (int j = 0; j < 16; ++j) {
        // afrag on demand (verified layout): elem e = U[m=n][k=q*8+e]; q>=2 zero
        bf16x8 af = (bf16x8)0;
        if (q < 2) {
            const float* Tp = T_lds + n * TS + j * 16 + q * 8;
            float4 t0 = *(const float4*)(Tp);
            float4 t1 = *(const float4*)(Tp + 4);
            af[0] = f2bf(t0.x); af[1] = f2bf(t0.y);
            af[2] = f2bf(t0.z); af[3] = f2bf(t0.w);
            af[4] = f2bf(t1.x); af[5] = f2bf(t1.y);
            af[6] = f2bf(t1.z); af[7] = f2bf(t1.w);
        }

        // MFMA per 16-col chunk; D(lane(q,n), reg) = out[row=q*4+reg][col=c*16+n]
        // -> write transposed into LDS tile (2-way banks = free)
#pragma unroll
        for (int c = 0; c < 8; ++c) {
            f32x4 d = {0.f, 0.f, 0.f, 0.f};
            d = __builtin_amdgcn_mfma_f32_16x16x32_bf16(af, bfrag[c], d, 0, 0, 0);
            float* tp = tw + c * 16 + n;
            tp[(q * 4 + 0) * TRS] = d[0];
            tp[(q * 4 + 1) * TRS] = d[1];
            tp[(q * 4 + 2) * TRS] = d[2];
            tp[(q * 4 + 3) * TRS] = d[3];
        }

        // read back coalesced; NONTEMPORAL stores: 512B contiguous per instr
        const int rrow = (lane >> 5);         // 0/1: row within pair
        const int c4   = (lane & 31) * 4;     // col offset within 128-col chunk
        float* ob = out + (size_t)row0 * DOUT + j * 512 + w * 128 + c4;
#pragma unroll
        for (int rp = 0; rp < 8; ++rp) {
            const int row = 2 * rp + rrow;
            f32x4 v = *(const f32x4*)(tw + row * TRS + c4);
            __builtin_nontemporal_store(v, (f32x4*)(ob + (size_t)row * DOUT));
        }
    }
}

extern "C" void kernel_launch(void* const* d_in, const int* in_sizes, int n_in,
                              void* d_out, int out_size, void* d_ws, size_t ws_size,
                              hipStream_t stream) {
    const float* x = (const float*)d_in[0];
    const float* A = (const float*)d_in[1];
    const float* B = (const float*)d_in[2];
    float* out = (float*)d_out;

    const int nrows = in_sizes[0] / DIN;      // 16384
    const int grid  = nrows / 16;             // 1024 blocks, 16 rows each

    kron_mfma3_kernel<<<dim3(grid), dim3(256), 0, stream>>>(x, A, B, out);
}